// Round 2
// baseline (1756.612 us; speedup 1.0000x reference)
//
#include <hip/hip_runtime.h>

// ---------------------------------------------------------------------------
// BLSTM: emb gather -> fwd LSTM scan + bwd single-step -> [2048,512] @ fc_w^T
// B=16 S=128 V=32000 D=H=256.  Output logits [16,128,32000] fp32.
//
// R2: k2 scan rebuilt as ONE workgroup per batch (16 blocks x 512 threads).
// R1's 4-blocks-per-batch design paid an agent-scope LLC release/acquire
// round trip per timestep (~10k of 11.5k cycles/step; VALUBusy 3.3%).
// Root cause of the split was capacity: W_hh fp32 (1 MB) > one CU's 512 KB
// register file.  Fix: W_hh compressed to f16 (512 KB) = 192 dwords/thread
// in VGPRs (384 KB) + 128 KB in LDS.  Per step: v_pk_fma_f16 dot (2 MACs/
// inst, 8 f16x2 chains, fp32 final sum), h exchanged via LDS with 2 raw
// barriers (lgkmcnt-only, no vmcnt drain -> xp prefetch survives barriers).
// No cross-CU communication anywhere in the scan.
//
// R3: resubmit of R2 (container failed twice, no counters).  Hang-hardening:
// bar() is now a SINGLE asm volatile("s_waitcnt lgkmcnt(0); s_barrier")
// with "memory" clobber -- nothing can be reordered across it at IR or MIR
// level, closing the only theoretical hang window (builtin s_barrier is not
// a memory fence).  No functional changes otherwise.
// ---------------------------------------------------------------------------

#define Bz 16
#define Sq 128
#define Vv 32000
#define Dd 256
#define Hh 256
#define Ktot  (2 * Hh)         // 512

typedef __bf16 bf16x8 __attribute__((ext_vector_type(8)));
typedef float  f32x4  __attribute__((ext_vector_type(4)));
typedef _Float16 f16x2 __attribute__((ext_vector_type(2)));

__device__ __forceinline__ unsigned short f2bf(float x) {
  union { float f; unsigned u; } v; v.f = x;
  unsigned r = (v.u + 0x7FFFu + ((v.u >> 16) & 1u)) >> 16;
  return (unsigned short)r;
}
__device__ __forceinline__ float sigm(float x) { return 1.f / (1.f + __expf(-x)); }
__device__ __forceinline__ float tanh_(float x) { return 2.f / (1.f + __expf(-2.f * x)) - 1.f; }
__device__ __forceinline__ void fma4(float4& a, const float4 w, const float s) {
  a.x = fmaf(w.x, s, a.x); a.y = fmaf(w.y, s, a.y);
  a.z = fmaf(w.z, s, a.z); a.w = fmaf(w.w, s, a.w);
}
__device__ __forceinline__ unsigned pkh(float x, float y) {
  const unsigned short lo = __builtin_bit_cast(unsigned short, (_Float16)x);
  const unsigned short hi = __builtin_bit_cast(unsigned short, (_Float16)y);
  return ((unsigned)hi << 16) | (unsigned)lo;
}
// packed f16 MAC: acc(v2f16) += w(v2f16) * h(v2f16)  -> v_pk_fma_f16
__device__ __forceinline__ f16x2 fma2(unsigned w, unsigned h, f16x2 acc) {
  const f16x2 wv = __builtin_bit_cast(f16x2, w);
  const f16x2 hv = __builtin_bit_cast(f16x2, h);
#if __has_builtin(__builtin_elementwise_fma)
  return __builtin_elementwise_fma(wv, hv, acc);
#else
  return wv * hv + acc;   // -ffp-contract fuses to v_pk_fma_f16
#endif
}
// LDS-only barrier: order ds ops, do NOT drain vmcnt (keeps global prefetch
// in flight across the barrier, unlike __syncthreads()).  Single asm block
// with "memory" clobber: no memory op can cross at IR or MIR level.
__device__ __forceinline__ void bar() {
  asm volatile("s_waitcnt lgkmcnt(0)\n\ts_barrier" ::: "memory");
}

// --------------------------------------------------------------------------
// K0: transpose+pack input weights to [k][j] float4 (i,f,g,o), fold biases.
// grid (256, 2), block 256.
// --------------------------------------------------------------------------
__global__ __launch_bounds__(256) void k0_pack(
    const float* __restrict__ w_ih_f, const float* __restrict__ w_ih_b,
    const float* __restrict__ b_ih_f, const float* __restrict__ b_hh_f,
    const float* __restrict__ b_ih_b, const float* __restrict__ b_hh_b,
    float4* __restrict__ wPackF, float4* __restrict__ wPackB,
    float4* __restrict__ biasF, float4* __restrict__ biasB)
{
  const int j = threadIdx.x;   // output column 0..255
  const int k = blockIdx.x;    // input dim 0..255
  const int g = blockIdx.y;    // 0: w_ih_f, 1: w_ih_b
  const float* src = (g == 0) ? w_ih_f : w_ih_b;
  float4* dst = (g == 0) ? wPackF : wPackB;
  float4 v;
  v.x = src[(j      ) * 256 + k];
  v.y = src[(j + 256) * 256 + k];
  v.z = src[(j + 512) * 256 + k];
  v.w = src[(j + 768) * 256 + k];
  dst[k * 256 + j] = v;
  if (k == 0 && g == 0) {
    float4 b;
    b.x = b_ih_f[j      ] + b_hh_f[j      ];
    b.y = b_ih_f[j + 256] + b_hh_f[j + 256];
    b.z = b_ih_f[j + 512] + b_hh_f[j + 512];
    b.w = b_ih_f[j + 768] + b_hh_f[j + 768];
    biasF[j] = b;
  }
  if (k == 0 && g == 1) {
    float4 b;
    b.x = b_ih_b[j      ] + b_hh_b[j      ];
    b.y = b_ih_b[j + 256] + b_hh_b[j + 256];
    b.z = b_ih_b[j + 512] + b_hh_b[j + 512];
    b.w = b_ih_b[j + 768] + b_hh_b[j + 768];
    biasB[j] = b;
  }
}

// --------------------------------------------------------------------------
// K1: embedding gather + input projections. grid (128, 2): y=0 -> xpG
// [m][1024] gate-row-major (biases folded), y=1 -> backward single-step
// cell -> hb (bf16, right half of the GEMM A matrix).
// --------------------------------------------------------------------------
__global__ __launch_bounds__(256) void k1_embproj(
    const int* __restrict__ x, const float* __restrict__ embed,
    const float4* __restrict__ wPackF, const float4* __restrict__ wPackB,
    const float4* __restrict__ biasF, const float4* __restrict__ biasB,
    float* __restrict__ xpG, unsigned short* __restrict__ outB)
{
  __shared__ __align__(16) float e[16][256];
  __shared__ int xi[16];
  const int j = threadIdx.x;
  const int m0 = blockIdx.x * 16;
  const int dir = blockIdx.y;
  if (j < 16) xi[j] = x[m0 + j];
  __syncthreads();
#pragma unroll
  for (int m = 0; m < 16; ++m) e[m][j] = embed[(size_t)xi[m] * Dd + j];
  __syncthreads();

  const float4* wP = dir ? wPackB : wPackF;
  float4 acc[16];
#pragma unroll
  for (int m = 0; m < 16; ++m) acc[m] = make_float4(0.f, 0.f, 0.f, 0.f);

  for (int k = 0; k < 256; k += 4) {
    const float4 w0 = wP[(k + 0) * 256 + j];
    const float4 w1 = wP[(k + 1) * 256 + j];
    const float4 w2 = wP[(k + 2) * 256 + j];
    const float4 w3 = wP[(k + 3) * 256 + j];
#pragma unroll
    for (int m = 0; m < 16; ++m) {
      const float4 e4 = *(const float4*)&e[m][k];
      fma4(acc[m], w0, e4.x); fma4(acc[m], w1, e4.y);
      fma4(acc[m], w2, e4.z); fma4(acc[m], w3, e4.w);
    }
  }

  if (dir == 0) {
    const float4 bv = biasF[j];
#pragma unroll
    for (int m = 0; m < 16; ++m) {
      float4 v = acc[m];
      float* xq = xpG + (size_t)(m0 + m) * 1024 + j;
      xq[0]   = v.x + bv.x;
      xq[256] = v.y + bv.y;
      xq[512] = v.z + bv.z;
      xq[768] = v.w + bv.w;
    }
  } else {
    const float4 bv = biasB[j];
#pragma unroll
    for (int m = 0; m < 16; ++m) {
      float4 v = acc[m];
      v.x += bv.x; v.y += bv.y; v.z += bv.z; v.w += bv.w;
      const float ig = sigm(v.x);
      const float gg = tanh_(v.z);
      const float og = sigm(v.w);
      const float hb = og * tanh_(ig * gg);
      outB[(size_t)(m0 + m) * Ktot + Hh + j] = f2bf(hb);
    }
  }
}

// --------------------------------------------------------------------------
// KW: W_hh fp32 [1024][256] -> packed f16, q-major layout [32][1024] uint4
// (q = k/8).  wq[q*1024 + row] = 8 f16 of row `row`, k in [8q, 8q+8).
// Write-coalesced; reads hit L2 (1 MB).  grid 128 x 256.
// --------------------------------------------------------------------------
__global__ __launch_bounds__(256) void kw_cvt(const float4* __restrict__ s,
                                              uint4* __restrict__ d)
{
  const int g = blockIdx.x * 256 + threadIdx.x;   // 0..32767
  const int row = g & 1023;
  const int qq  = g >> 10;                        // 0..31
  const float4 a = s[row * 64 + qq * 2];
  const float4 b = s[row * 64 + qq * 2 + 1];
  uint4 r;
  r.x = pkh(a.x, a.y);
  r.y = pkh(a.z, a.w);
  r.z = pkh(b.x, b.y);
  r.w = pkh(b.z, b.w);
  d[g] = r;
}

// --------------------------------------------------------------------------
// K2f: forward LSTM scan, ONE block per batch (16 blocks x 512 threads).
// Thread (u = tid&255, p = tid>>8) owns gate rows p*512+u and p*512+256+u:
//   p=0 -> i,f rows (also owns the cell state c and publishes h)
//   p=1 -> g,o rows (publishes preacts via LDS)
// Weights: rows packed f16; row_a (32 uint4) + row_b[0:16] (16 uint4) in
// VGPRs, row_b[16:32] in LDS (128 KB, lane-consecutive 16B -> conflict-free).
// h (f16) broadcast from LDS; per-step sync = 2 in-CU barriers only.
// --------------------------------------------------------------------------
__global__ __launch_bounds__(512, 2) void k2f(
    const uint4* __restrict__ wq,     // [32][1024] uint4 packed f16 W_hh
    const float* __restrict__ xpG,    // [2048][1024]
    unsigned short* __restrict__ outB)
{
  __shared__ __align__(16) uint4 wl[16 * 512];        // 128 KB: row_b k in [128,256)
  __shared__ __align__(16) unsigned short hL[256];    // h_{t-1} as f16 bits
  __shared__ float gx[256];                           // g-gate preacts
  __shared__ float ox[256];                           // o-gate preacts

  const int tid = threadIdx.x;
  const int u = tid & 255;
  const int p = tid >> 8;
  const int b = blockIdx.x;
  const int row_a = p * 512 + u;        // gate i (p=0) / g (p=1)
  const int row_b = row_a + 256;        // gate f (p=0) / o (p=1)

  // one-time: weights into VGPRs + LDS (coalesced: lanes u consecutive)
  uint4 wa4[32], wb4[16];
#pragma unroll
  for (int q = 0; q < 32; ++q) wa4[q] = wq[q * 1024 + row_a];
#pragma unroll
  for (int q = 0; q < 16; ++q) wb4[q] = wq[q * 1024 + row_b];
#pragma unroll
  for (int c = 0; c < 16; ++c) wl[c * 512 + tid] = wq[(16 + c) * 1024 + row_b];
  if (tid < 32) ((uint4*)hL)[tid] = make_uint4(0, 0, 0, 0);   // h_{-1} = 0

  const float* xpB = xpG + (size_t)b * Sq * 1024;
  float xa = xpB[row_a];                // xp prefetch for t=0
  float xb = xpB[row_b];
  float cst = 0.f;                      // cell state (p=0 threads)
  unsigned short* oB = outB + (size_t)b * Sq * Ktot;

  bar();   // weights staged + hL zeroed

  const uint4* hv4 = (const uint4*)hL;
  const f16x2 z2 = __builtin_bit_cast(f16x2, 0u);

#pragma unroll 1
  for (int t = 0; t < Sq; ++t) {
    // dot: 512 MACs/thread as 256 v_pk_fma_f16, 8 independent chains
    f16x2 cA0 = z2, cA1 = z2, cA2 = z2, cA3 = z2;
    f16x2 cB0 = z2, cB1 = z2, cB2 = z2, cB3 = z2;
#pragma unroll
    for (int q = 0; q < 16; ++q) {
      const uint4 h4 = hv4[q];          // broadcast (uniform address)
      const uint4 wA = wa4[q];
      const uint4 wB = wb4[q];
      cA0 = fma2(wA.x, h4.x, cA0); cA1 = fma2(wA.y, h4.y, cA1);
      cA2 = fma2(wA.z, h4.z, cA2); cA3 = fma2(wA.w, h4.w, cA3);
      cB0 = fma2(wB.x, h4.x, cB0); cB1 = fma2(wB.y, h4.y, cB1);
      cB2 = fma2(wB.z, h4.z, cB2); cB3 = fma2(wB.w, h4.w, cB3);
    }
#pragma unroll
    for (int q = 16; q < 32; ++q) {
      const uint4 h4 = hv4[q];
      const uint4 wA = wa4[q];
      const uint4 wB = wl[(q - 16) * 512 + tid];   // conflict-free 16B/lane
      cA0 = fma2(wA.x, h4.x, cA0); cA1 = fma2(wA.y, h4.y, cA1);
      cA2 = fma2(wA.z, h4.z, cA2); cA3 = fma2(wA.w, h4.w, cA3);
      cB0 = fma2(wB.x, h4.x, cB0); cB1 = fma2(wB.y, h4.y, cB1);
      cB2 = fma2(wB.z, h4.z, cB2); cB3 = fma2(wB.w, h4.w, cB3);
    }
    const float preA = xa
        + ((float)cA0.x + (float)cA0.y) + ((float)cA1.x + (float)cA1.y)
        + ((float)cA2.x + (float)cA2.y) + ((float)cA3.x + (float)cA3.y);
    const float preB = xb
        + ((float)cB0.x + (float)cB0.y) + ((float)cB1.x + (float)cB1.y)
        + ((float)cB2.x + (float)cB2.y) + ((float)cB3.x + (float)cB3.y);

    // prefetch next step's xp (stays in flight: bar() doesn't drain vmcnt)
    if (t + 1 < Sq) {
      xa = xpB[(size_t)(t + 1) * 1024 + row_a];
      xb = xpB[(size_t)(t + 1) * 1024 + row_b];
    }

    if (p) { gx[u] = preA; ox[u] = preB; }
    bar();   // #1: preacts visible; all hL reads of step t done

    if (!p) {
      const float ig = sigm(preA);        // i
      const float fg = sigm(preB);        // f
      const float gg = tanh_(gx[u]);      // g
      const float og = sigm(ox[u]);       // o
      cst = fg * cst + ig * gg;
      const float hn = og * tanh_(cst);
      hL[u] = __builtin_bit_cast(unsigned short, (_Float16)hn);
      oB[t * Ktot + u] = f2bf(hn);
    }
    bar();   // #2: h_t published for step t+1
  }
}

// --------------------------------------------------------------------------
// K3: fc_w fp32 -> bf16.  16,384,000 elems; 4 per thread.
// --------------------------------------------------------------------------
__global__ __launch_bounds__(256) void k3_cvt(const float4* __restrict__ s,
                                              uint2* __restrict__ d)
{
  const int i = blockIdx.x * 256 + threadIdx.x;
  const float4 v = s[i];
  uint2 r;
  r.x = (unsigned)f2bf(v.x) | ((unsigned)f2bf(v.y) << 16);
  r.y = (unsigned)f2bf(v.z) | ((unsigned)f2bf(v.w) << 16);
  d[i] = r;
}

// --------------------------------------------------------------------------
// K4: logits = [2048,512](bf16) x fc_w^T (fc_w [32000,512] bf16, B^T layout)
// + fc_b.  128x128 tile, BK=64, 4 waves, global_load_lds width-16 staging.
// --------------------------------------------------------------------------
__device__ __forceinline__ void load_lds_16(const void* g, void* l) {
  __builtin_amdgcn_global_load_lds(
      (const __attribute__((address_space(1))) unsigned int*)g,
      (__attribute__((address_space(3))) unsigned int*)l, 16, 0, 0);
}

__global__ __launch_bounds__(256) void k4_gemm(
    const unsigned short* __restrict__ A,   // [2048][512] bf16
    const unsigned short* __restrict__ Bm,  // [32000][512] bf16
    const float* __restrict__ fcb,          // [32000]
    float* __restrict__ out)                // [2048][32000]
{
  __shared__ __align__(16) char smem[32768];
  const int tid  = threadIdx.x;
  const int wave = tid >> 6;
  const int lane = tid & 63;
  const int bm = blockIdx.x;      // 0..15  (M tiles)
  const int bn = blockIdx.y;      // 0..249 (N tiles)
  const int wm = (wave >> 1) * 64;
  const int wn = (wave & 1) * 64;
  const int quad = lane >> 4;
  const int r16  = lane & 15;

  f32x4 acc[4][4] = {};

  const unsigned short* Ag = A  + ((size_t)(bm * 128) + (tid >> 3)) * Ktot + (tid & 7) * 8;
  const unsigned short* Bg = Bm + ((size_t)(bn * 128) + (tid >> 3)) * Ktot + (tid & 7) * 8;
  char* AsW = smem + wave * 1024;
  char* BsW = smem + 16384 + wave * 1024;

  for (int kt = 0; kt < 8; ++kt) {
    const int k0 = kt * 64;
#pragma unroll
    for (int r = 0; r < 4; ++r) {
      load_lds_16(Ag + (size_t)r * 32 * Ktot + k0, AsW + r * 4096);
      load_lds_16(Bg + (size_t)r * 32 * Ktot + k0, BsW + r * 4096);
    }
    __syncthreads();
#pragma unroll
    for (int kk = 0; kk < 2; ++kk) {
      bf16x8 af[4], bfr[4];
#pragma unroll
      for (int i = 0; i < 4; ++i) {
        const int rowA = wm + i * 16 + r16;
        af[i] = *(const bf16x8*)(smem + rowA * 128 + kk * 64 + quad * 16);
        const int rowB = wn + i * 16 + r16;
        bfr[i] = *(const bf16x8*)(smem + 16384 + rowB * 128 + kk * 64 + quad * 16);
      }
#pragma unroll
      for (int i = 0; i < 4; ++i)
#pragma unroll
        for (int j = 0; j < 4; ++j)
          acc[i][j] = __builtin_amdgcn_mfma_f32_16x16x32_bf16(af[i], bfr[j], acc[i][j], 0, 0, 0);
    }
    __syncthreads();
  }

#pragma unroll
  for (int j = 0; j < 4; ++j) {
    const int col = bn * 128 + wn + j * 16 + r16;
    const float bias = fcb[col];
#pragma unroll
    for (int i = 0; i < 4; ++i) {
      const int row0 = bm * 128 + wm + i * 16 + quad * 4;
#pragma unroll
      for (int r = 0; r < 4; ++r) {
        out[(size_t)(row0 + r) * Vv + col] = acc[i][j][r] + bias;
      }
    }
  }
}

// --------------------------------------------------------------------------
extern "C" void kernel_launch(void* const* d_in, const int* in_sizes, int n_in,
                              void* d_out, int out_size, void* d_ws, size_t ws_size,
                              hipStream_t stream) {
  const int*   x      = (const int*)d_in[0];
  const float* embed  = (const float*)d_in[1];
  const float* w_ih_f = (const float*)d_in[2];
  const float* w_hh_f = (const float*)d_in[3];
  const float* b_ih_f = (const float*)d_in[4];
  const float* b_hh_f = (const float*)d_in[5];
  const float* w_ih_b = (const float*)d_in[6];
  // d_in[7] = w_hh_b: unused (backward direction is a zero-state single step)
  const float* b_ih_b = (const float*)d_in[8];
  const float* b_hh_b = (const float*)d_in[9];
  const float* fc_w   = (const float*)d_in[10];
  const float* fc_b   = (const float*)d_in[11];
  float* out = (float*)d_out;

  // Workspace layout (peak 45.4 MB; wq overlays wPackF which is dead after
  // k1 -- kw_cvt MUST launch after k1):
  char* ws = (char*)d_ws;
  float4* wPackF = (float4*)(ws + 0x000000);            // 1 MB   (k0 w, k1 r)
  float4* wPackB = (float4*)(ws + 0x100000);            // 1 MB   (k0 w, k1 r)
  uint4*  wq     = (uint4*)(ws + 0x000000);             // 512 KB (kw w, k2 r)
  float*  xpG    = (float*)(ws + 0x200000);             // 8 MB   (k1 w, k2 r)
  float4* biasF  = (float4*)(ws + 0xA00000);            // 4 KB
  float4* biasB  = (float4*)(ws + 0xA01000);            // 4 KB
  unsigned short* outB = (unsigned short*)(ws + 0xA05000);   // 2 MB [2048][512]
  unsigned short* fcwB = (unsigned short*)(ws + 0xC05000);   // 31.25 MiB

  k0_pack<<<dim3(256, 2), 256, 0, stream>>>(w_ih_f, w_ih_b,
                                            b_ih_f, b_hh_f, b_ih_b, b_hh_b,
                                            wPackF, wPackB, biasF, biasB);
  k3_cvt<<<16000, 256, 0, stream>>>((const float4*)fc_w, (uint2*)fcwB);
  k1_embproj<<<dim3(128, 2), 256, 0, stream>>>(x, embed, wPackF, wPackB,
                                               biasF, biasB, xpG, outB);
  kw_cvt<<<128, 256, 0, stream>>>((const float4*)w_hh_f, wq);
  k2f<<<16, 512, 0, stream>>>(wq, xpG, outB);
  k4_gemm<<<dim3(16, 250), 256, 0, stream>>>(outB, fcwB, fc_b, out);
}

// Round 3
// 946.147 us; speedup vs baseline: 1.8566x; 1.8566x over previous
//
#include <hip/hip_runtime.h>

// ---------------------------------------------------------------------------
// BLSTM: emb gather -> fwd LSTM scan + bwd single-step -> [2048,512] @ fc_w^T
// B=16 S=128 V=32000 D=H=256.  Output logits [16,128,32000] fp32.
//
// R4: k2 scan rebuilt (k2g).  R3's k2f regressed to 1270us because
// __launch_bounds__(512,2) capped VGPRs at 128 (measured VGPR_Count=128) and
// the 192-reg weight arrays were demoted to scratch -> per-step scratch
// reload, VALUBusy 0.8%.  New design: 256 threads/block (1 block/batch),
// __launch_bounds__(256,1) -> 1 wave/SIMD -> VGPR cap 512.  Thread u owns
// ALL FOUR gate rows of hidden unit u (i,f,g,o) -> gate combine is fully
// thread-local (no shuffles, no preact LDS).  Weights f16: 92 uint4 (368
// VGPR, 80% of cap) + 36 uint4/thread in LDS (144 KB).  h exchanged via
// double-buffered 512B LDS array -> ONE lgkmcnt-only barrier per step; xp
// prefetch (vmcnt) stays in flight across it.  Per-step per-CU: VALU ~1250cy,
// LDS pipe ~3300cy (bound) -> ~1.4us/step, k2 ~200us predicted.
// ---------------------------------------------------------------------------

#define Bz 16
#define Sq 128
#define Vv 32000
#define Dd 256
#define Hh 256
#define Ktot  (2 * Hh)         // 512

#define NW_V 23   // weight chunks (uint4 of 8 f16) per row held in VGPRs
#define NW_L 9    // weight chunks per row held in LDS   (NW_V+NW_L == 32)

typedef __bf16 bf16x8 __attribute__((ext_vector_type(8)));
typedef float  f32x4  __attribute__((ext_vector_type(4)));
typedef _Float16 f16x2 __attribute__((ext_vector_type(2)));

__device__ __forceinline__ unsigned short f2bf(float x) {
  union { float f; unsigned u; } v; v.f = x;
  unsigned r = (v.u + 0x7FFFu + ((v.u >> 16) & 1u)) >> 16;
  return (unsigned short)r;
}
__device__ __forceinline__ float sigm(float x) { return 1.f / (1.f + __expf(-x)); }
__device__ __forceinline__ float tanh_(float x) { return 2.f / (1.f + __expf(-2.f * x)) - 1.f; }
__device__ __forceinline__ void fma4(float4& a, const float4 w, const float s) {
  a.x = fmaf(w.x, s, a.x); a.y = fmaf(w.y, s, a.y);
  a.z = fmaf(w.z, s, a.z); a.w = fmaf(w.w, s, a.w);
}
__device__ __forceinline__ unsigned pkh(float x, float y) {
  const unsigned short lo = __builtin_bit_cast(unsigned short, (_Float16)x);
  const unsigned short hi = __builtin_bit_cast(unsigned short, (_Float16)y);
  return ((unsigned)hi << 16) | (unsigned)lo;
}
// packed f16 MAC: acc(v2f16) += w(v2f16) * h(v2f16)  -> v_pk_fma_f16
__device__ __forceinline__ f16x2 fma2(unsigned w, unsigned h, f16x2 acc) {
  const f16x2 wv = __builtin_bit_cast(f16x2, w);
  const f16x2 hv = __builtin_bit_cast(f16x2, h);
#if __has_builtin(__builtin_elementwise_fma)
  return __builtin_elementwise_fma(wv, hv, acc);
#else
  return wv * hv + acc;   // -ffp-contract fuses to v_pk_fma_f16
#endif
}
// LDS-only barrier: order ds ops, do NOT drain vmcnt (keeps global prefetch
// in flight across the barrier).  Single asm block with "memory" clobber.
__device__ __forceinline__ void bar() {
  asm volatile("s_waitcnt lgkmcnt(0)\n\ts_barrier" ::: "memory");
}

// --------------------------------------------------------------------------
// K0: transpose+pack input weights to [k][j] float4 (i,f,g,o), fold biases.
// grid (256, 2), block 256.
// --------------------------------------------------------------------------
__global__ __launch_bounds__(256) void k0_pack(
    const float* __restrict__ w_ih_f, const float* __restrict__ w_ih_b,
    const float* __restrict__ b_ih_f, const float* __restrict__ b_hh_f,
    const float* __restrict__ b_ih_b, const float* __restrict__ b_hh_b,
    float4* __restrict__ wPackF, float4* __restrict__ wPackB,
    float4* __restrict__ biasF, float4* __restrict__ biasB)
{
  const int j = threadIdx.x;   // output column 0..255
  const int k = blockIdx.x;    // input dim 0..255
  const int g = blockIdx.y;    // 0: w_ih_f, 1: w_ih_b
  const float* src = (g == 0) ? w_ih_f : w_ih_b;
  float4* dst = (g == 0) ? wPackF : wPackB;
  float4 v;
  v.x = src[(j      ) * 256 + k];
  v.y = src[(j + 256) * 256 + k];
  v.z = src[(j + 512) * 256 + k];
  v.w = src[(j + 768) * 256 + k];
  dst[k * 256 + j] = v;
  if (k == 0 && g == 0) {
    float4 b;
    b.x = b_ih_f[j      ] + b_hh_f[j      ];
    b.y = b_ih_f[j + 256] + b_hh_f[j + 256];
    b.z = b_ih_f[j + 512] + b_hh_f[j + 512];
    b.w = b_ih_f[j + 768] + b_hh_f[j + 768];
    biasF[j] = b;
  }
  if (k == 0 && g == 1) {
    float4 b;
    b.x = b_ih_b[j      ] + b_hh_b[j      ];
    b.y = b_ih_b[j + 256] + b_hh_b[j + 256];
    b.z = b_ih_b[j + 512] + b_hh_b[j + 512];
    b.w = b_ih_b[j + 768] + b_hh_b[j + 768];
    biasB[j] = b;
  }
}

// --------------------------------------------------------------------------
// K1: embedding gather + input projections. grid (128, 2): y=0 -> xpG
// [m][1024] gate-row-major (biases folded), y=1 -> backward single-step
// cell -> hb (bf16, right half of the GEMM A matrix).
// --------------------------------------------------------------------------
__global__ __launch_bounds__(256) void k1_embproj(
    const int* __restrict__ x, const float* __restrict__ embed,
    const float4* __restrict__ wPackF, const float4* __restrict__ wPackB,
    const float4* __restrict__ biasF, const float4* __restrict__ biasB,
    float* __restrict__ xpG, unsigned short* __restrict__ outB)
{
  __shared__ __align__(16) float e[16][256];
  __shared__ int xi[16];
  const int j = threadIdx.x;
  const int m0 = blockIdx.x * 16;
  const int dir = blockIdx.y;
  if (j < 16) xi[j] = x[m0 + j];
  __syncthreads();
#pragma unroll
  for (int m = 0; m < 16; ++m) e[m][j] = embed[(size_t)xi[m] * Dd + j];
  __syncthreads();

  const float4* wP = dir ? wPackB : wPackF;
  float4 acc[16];
#pragma unroll
  for (int m = 0; m < 16; ++m) acc[m] = make_float4(0.f, 0.f, 0.f, 0.f);

  for (int k = 0; k < 256; k += 4) {
    const float4 w0 = wP[(k + 0) * 256 + j];
    const float4 w1 = wP[(k + 1) * 256 + j];
    const float4 w2 = wP[(k + 2) * 256 + j];
    const float4 w3 = wP[(k + 3) * 256 + j];
#pragma unroll
    for (int m = 0; m < 16; ++m) {
      const float4 e4 = *(const float4*)&e[m][k];
      fma4(acc[m], w0, e4.x); fma4(acc[m], w1, e4.y);
      fma4(acc[m], w2, e4.z); fma4(acc[m], w3, e4.w);
    }
  }

  if (dir == 0) {
    const float4 bv = biasF[j];
#pragma unroll
    for (int m = 0; m < 16; ++m) {
      float4 v = acc[m];
      float* xq = xpG + (size_t)(m0 + m) * 1024 + j;
      xq[0]   = v.x + bv.x;
      xq[256] = v.y + bv.y;
      xq[512] = v.z + bv.z;
      xq[768] = v.w + bv.w;
    }
  } else {
    const float4 bv = biasB[j];
#pragma unroll
    for (int m = 0; m < 16; ++m) {
      float4 v = acc[m];
      v.x += bv.x; v.y += bv.y; v.z += bv.z; v.w += bv.w;
      const float ig = sigm(v.x);
      const float gg = tanh_(v.z);
      const float og = sigm(v.w);
      const float hb = og * tanh_(ig * gg);
      outB[(size_t)(m0 + m) * Ktot + Hh + j] = f2bf(hb);
    }
  }
}

// --------------------------------------------------------------------------
// KW: W_hh fp32 [1024][256] -> packed f16, q-major layout [32][1024] uint4
// (q = k/8).  wq[q*1024 + row] = 8 f16 of row `row`, k in [8q, 8q+8).
// Write-coalesced; reads hit L2 (1 MB).  grid 128 x 256.
// --------------------------------------------------------------------------
__global__ __launch_bounds__(256) void kw_cvt(const float4* __restrict__ s,
                                              uint4* __restrict__ d)
{
  const int g = blockIdx.x * 256 + threadIdx.x;   // 0..32767
  const int row = g & 1023;
  const int qq  = g >> 10;                        // 0..31
  const float4 a = s[row * 64 + qq * 2];
  const float4 b = s[row * 64 + qq * 2 + 1];
  uint4 r;
  r.x = pkh(a.x, a.y);
  r.y = pkh(a.z, a.w);
  r.z = pkh(b.x, b.y);
  r.w = pkh(b.z, b.w);
  d[g] = r;
}

// --------------------------------------------------------------------------
// K2g: forward LSTM scan, ONE block per batch (16 blocks x 256 threads,
// 1 wave/SIMD -> VGPR cap 512).  Thread u owns rows {u,256+u,512+u,768+u}
// = gates i,f,g,o of hidden unit u: gate combine is thread-local.
// Weights: per row, q-chunks [0,NW_V) in VGPRs (92 uint4 = 368 regs),
// [NW_V,32) in LDS (144 KB, lane-consecutive 16B -> conflict-free).
// h (f16) double-buffered in LDS; ONE lgkmcnt-only barrier per step.
// --------------------------------------------------------------------------
__global__ __launch_bounds__(256, 1) void k2g(
    const uint4* __restrict__ wq,     // [32][1024] uint4 packed f16 W_hh
    const float* __restrict__ xpG,    // [2048][1024]
    unsigned short* __restrict__ outB)
{
  __shared__ __align__(16) uint4 wl[4 * NW_L * 256];     // 147456 B
  __shared__ __align__(16) unsigned short hL[2][256];    // double-buffered h

  const int u = threadIdx.x;
  const int b = blockIdx.x;

  // one-time: weights into VGPRs (92 uint4) -- coalesced (lanes consecutive)
  uint4 wv[4][NW_V];
#pragma unroll
  for (int r = 0; r < 4; ++r)
#pragma unroll
    for (int q = 0; q < NW_V; ++q)
      wv[r][q] = wq[q * 1024 + r * 256 + u];
  // one-time: weight tail into LDS (36 uint4/thread)
#pragma unroll
  for (int r = 0; r < 4; ++r)
#pragma unroll
    for (int j = 0; j < NW_L; ++j)
      wl[(r * NW_L + j) * 256 + u] = wq[(NW_V + j) * 1024 + r * 256 + u];

  hL[0][u] = 0;                       // h_{-1} = 0 (buffer 0 feeds t=0)

  const float* xpB = xpG + (size_t)b * Sq * 1024;
  float xp0 = xpB[u];                 // xp prefetch for t=0 (i,f,g,o)
  float xp1 = xpB[256 + u];
  float xp2 = xpB[512 + u];
  float xp3 = xpB[768 + u];
  float cst = 0.f;
  unsigned short* oB = outB + (size_t)b * Sq * Ktot;

  bar();   // weights staged + hL[0] zeroed

  const f16x2 z2 = __builtin_bit_cast(f16x2, 0u);

#pragma unroll 1
  for (int t = 0; t < Sq; ++t) {
    const uint4* hv = (const uint4*)hL[t & 1];
    // 4 rows x 4 independent f16x2 chains; one h4 broadcast feeds 16 MACs
    f16x2 a0x = z2, a0y = z2, a0z = z2, a0w = z2;
    f16x2 a1x = z2, a1y = z2, a1z = z2, a1w = z2;
    f16x2 a2x = z2, a2y = z2, a2z = z2, a2w = z2;
    f16x2 a3x = z2, a3y = z2, a3z = z2, a3w = z2;
#pragma unroll
    for (int q = 0; q < NW_V; ++q) {
      const uint4 h4 = hv[q];                 // uniform-address broadcast
      a0x = fma2(wv[0][q].x, h4.x, a0x); a0y = fma2(wv[0][q].y, h4.y, a0y);
      a0z = fma2(wv[0][q].z, h4.z, a0z); a0w = fma2(wv[0][q].w, h4.w, a0w);
      a1x = fma2(wv[1][q].x, h4.x, a1x); a1y = fma2(wv[1][q].y, h4.y, a1y);
      a1z = fma2(wv[1][q].z, h4.z, a1z); a1w = fma2(wv[1][q].w, h4.w, a1w);
      a2x = fma2(wv[2][q].x, h4.x, a2x); a2y = fma2(wv[2][q].y, h4.y, a2y);
      a2z = fma2(wv[2][q].z, h4.z, a2z); a2w = fma2(wv[2][q].w, h4.w, a2w);
      a3x = fma2(wv[3][q].x, h4.x, a3x); a3y = fma2(wv[3][q].y, h4.y, a3y);
      a3z = fma2(wv[3][q].z, h4.z, a3z); a3w = fma2(wv[3][q].w, h4.w, a3w);
    }
#pragma unroll
    for (int j = 0; j < NW_L; ++j) {
      const uint4 h4 = hv[NW_V + j];
      const uint4 w0 = wl[(0 * NW_L + j) * 256 + u];
      const uint4 w1 = wl[(1 * NW_L + j) * 256 + u];
      const uint4 w2 = wl[(2 * NW_L + j) * 256 + u];
      const uint4 w3 = wl[(3 * NW_L + j) * 256 + u];
      a0x = fma2(w0.x, h4.x, a0x); a0y = fma2(w0.y, h4.y, a0y);
      a0z = fma2(w0.z, h4.z, a0z); a0w = fma2(w0.w, h4.w, a0w);
      a1x = fma2(w1.x, h4.x, a1x); a1y = fma2(w1.y, h4.y, a1y);
      a1z = fma2(w1.z, h4.z, a1z); a1w = fma2(w1.w, h4.w, a1w);
      a2x = fma2(w2.x, h4.x, a2x); a2y = fma2(w2.y, h4.y, a2y);
      a2z = fma2(w2.z, h4.z, a2z); a2w = fma2(w2.w, h4.w, a2w);
      a3x = fma2(w3.x, h4.x, a3x); a3y = fma2(w3.y, h4.y, a3y);
      a3z = fma2(w3.z, h4.z, a3z); a3w = fma2(w3.w, h4.w, a3w);
    }
    const float pi = xp0
        + (((float)a0x.x + (float)a0x.y) + ((float)a0y.x + (float)a0y.y))
        + (((float)a0z.x + (float)a0z.y) + ((float)a0w.x + (float)a0w.y));
    const float pf = xp1
        + (((float)a1x.x + (float)a1x.y) + ((float)a1y.x + (float)a1y.y))
        + (((float)a1z.x + (float)a1z.y) + ((float)a1w.x + (float)a1w.y));
    const float pg = xp2
        + (((float)a2x.x + (float)a2x.y) + ((float)a2y.x + (float)a2y.y))
        + (((float)a2z.x + (float)a2z.y) + ((float)a2w.x + (float)a2w.y));
    const float po = xp3
        + (((float)a3x.x + (float)a3x.y) + ((float)a3y.x + (float)a3y.y))
        + (((float)a3z.x + (float)a3z.y) + ((float)a3w.x + (float)a3w.y));

    // prefetch next step's xp (vmcnt -- survives the lgkmcnt-only barrier)
    if (t + 1 < Sq) {
      const float* xn = xpB + (size_t)(t + 1) * 1024;
      xp0 = xn[u]; xp1 = xn[256 + u]; xp2 = xn[512 + u]; xp3 = xn[768 + u];
    }

    const float ig = sigm(pi);
    const float fg = sigm(pf);
    const float gg = tanh_(pg);
    const float og = sigm(po);
    cst = fg * cst + ig * gg;
    const float hn = og * tanh_(cst);
    hL[(t + 1) & 1][u] = __builtin_bit_cast(unsigned short, (_Float16)hn);
    oB[t * Ktot + u] = f2bf(hn);

    bar();   // h_t published; all hL reads of step t complete
  }
}

// --------------------------------------------------------------------------
// K3: fc_w fp32 -> bf16.  16,384,000 elems; 4 per thread.
// --------------------------------------------------------------------------
__global__ __launch_bounds__(256) void k3_cvt(const float4* __restrict__ s,
                                              uint2* __restrict__ d)
{
  const int i = blockIdx.x * 256 + threadIdx.x;
  const float4 v = s[i];
  uint2 r;
  r.x = (unsigned)f2bf(v.x) | ((unsigned)f2bf(v.y) << 16);
  r.y = (unsigned)f2bf(v.z) | ((unsigned)f2bf(v.w) << 16);
  d[i] = r;
}

// --------------------------------------------------------------------------
// K4: logits = [2048,512](bf16) x fc_w^T (fc_w [32000,512] bf16, B^T layout)
// + fc_b.  128x128 tile, BK=64, 4 waves, global_load_lds width-16 staging.
// --------------------------------------------------------------------------
__device__ __forceinline__ void load_lds_16(const void* g, void* l) {
  __builtin_amdgcn_global_load_lds(
      (const __attribute__((address_space(1))) unsigned int*)g,
      (__attribute__((address_space(3))) unsigned int*)l, 16, 0, 0);
}

__global__ __launch_bounds__(256) void k4_gemm(
    const unsigned short* __restrict__ A,   // [2048][512] bf16
    const unsigned short* __restrict__ Bm,  // [32000][512] bf16
    const float* __restrict__ fcb,          // [32000]
    float* __restrict__ out)                // [2048][32000]
{
  __shared__ __align__(16) char smem[32768];
  const int tid  = threadIdx.x;
  const int wave = tid >> 6;
  const int lane = tid & 63;
  const int bm = blockIdx.x;      // 0..15  (M tiles)
  const int bn = blockIdx.y;      // 0..249 (N tiles)
  const int wm = (wave >> 1) * 64;
  const int wn = (wave & 1) * 64;
  const int quad = lane >> 4;
  const int r16  = lane & 15;

  f32x4 acc[4][4] = {};

  const unsigned short* Ag = A  + ((size_t)(bm * 128) + (tid >> 3)) * Ktot + (tid & 7) * 8;
  const unsigned short* Bg = Bm + ((size_t)(bn * 128) + (tid >> 3)) * Ktot + (tid & 7) * 8;
  char* AsW = smem + wave * 1024;
  char* BsW = smem + 16384 + wave * 1024;

  for (int kt = 0; kt < 8; ++kt) {
    const int k0 = kt * 64;
#pragma unroll
    for (int r = 0; r < 4; ++r) {
      load_lds_16(Ag + (size_t)r * 32 * Ktot + k0, AsW + r * 4096);
      load_lds_16(Bg + (size_t)r * 32 * Ktot + k0, BsW + r * 4096);
    }
    __syncthreads();
#pragma unroll
    for (int kk = 0; kk < 2; ++kk) {
      bf16x8 af[4], bfr[4];
#pragma unroll
      for (int i = 0; i < 4; ++i) {
        const int rowA = wm + i * 16 + r16;
        af[i] = *(const bf16x8*)(smem + rowA * 128 + kk * 64 + quad * 16);
        const int rowB = wn + i * 16 + r16;
        bfr[i] = *(const bf16x8*)(smem + 16384 + rowB * 128 + kk * 64 + quad * 16);
      }
#pragma unroll
      for (int i = 0; i < 4; ++i)
#pragma unroll
        for (int j = 0; j < 4; ++j)
          acc[i][j] = __builtin_amdgcn_mfma_f32_16x16x32_bf16(af[i], bfr[j], acc[i][j], 0, 0, 0);
    }
    __syncthreads();
  }

#pragma unroll
  for (int j = 0; j < 4; ++j) {
    const int col = bn * 128 + wn + j * 16 + r16;
    const float bias = fcb[col];
#pragma unroll
    for (int i = 0; i < 4; ++i) {
      const int row0 = bm * 128 + wm + i * 16 + quad * 4;
#pragma unroll
      for (int r = 0; r < 4; ++r) {
        out[(size_t)(row0 + r) * Vv + col] = acc[i][j][r] + bias;
      }
    }
  }
}

// --------------------------------------------------------------------------
extern "C" void kernel_launch(void* const* d_in, const int* in_sizes, int n_in,
                              void* d_out, int out_size, void* d_ws, size_t ws_size,
                              hipStream_t stream) {
  const int*   x      = (const int*)d_in[0];
  const float* embed  = (const float*)d_in[1];
  const float* w_ih_f = (const float*)d_in[2];
  const float* w_hh_f = (const float*)d_in[3];
  const float* b_ih_f = (const float*)d_in[4];
  const float* b_hh_f = (const float*)d_in[5];
  const float* w_ih_b = (const float*)d_in[6];
  // d_in[7] = w_hh_b: unused (backward direction is a zero-state single step)
  const float* b_ih_b = (const float*)d_in[8];
  const float* b_hh_b = (const float*)d_in[9];
  const float* fc_w   = (const float*)d_in[10];
  const float* fc_b   = (const float*)d_in[11];
  float* out = (float*)d_out;

  // Workspace layout (peak 45.4 MB; wq overlays wPackF which is dead after
  // k1 -- kw_cvt MUST launch after k1):
  char* ws = (char*)d_ws;
  float4* wPackF = (float4*)(ws + 0x000000);            // 1 MB   (k0 w, k1 r)
  float4* wPackB = (float4*)(ws + 0x100000);            // 1 MB   (k0 w, k1 r)
  uint4*  wq     = (uint4*)(ws + 0x000000);             // 512 KB (kw w, k2 r)
  float*  xpG    = (float*)(ws + 0x200000);             // 8 MB   (k1 w, k2 r)
  float4* biasF  = (float4*)(ws + 0xA00000);            // 4 KB
  float4* biasB  = (float4*)(ws + 0xA01000);            // 4 KB
  unsigned short* outB = (unsigned short*)(ws + 0xA05000);   // 2 MB [2048][512]
  unsigned short* fcwB = (unsigned short*)(ws + 0xC05000);   // 31.25 MiB

  k0_pack<<<dim3(256, 2), 256, 0, stream>>>(w_ih_f, w_ih_b,
                                            b_ih_f, b_hh_f, b_ih_b, b_hh_b,
                                            wPackF, wPackB, biasF, biasB);
  k3_cvt<<<16000, 256, 0, stream>>>((const float4*)fc_w, (uint2*)fcwB);
  k1_embproj<<<dim3(128, 2), 256, 0, stream>>>(x, embed, wPackF, wPackB,
                                               biasF, biasB, xpG, outB);
  kw_cvt<<<128, 256, 0, stream>>>((const float4*)w_hh_f, wq);
  k2g<<<16, 256, 0, stream>>>(wq, xpG, outB);
  k4_gemm<<<dim3(16, 250), 256, 0, stream>>>(outB, fcwB, fc_b, out);
}

// Round 4
// 748.523 us; speedup vs baseline: 2.3468x; 1.2640x over previous
//
#include <hip/hip_runtime.h>

// ---------------------------------------------------------------------------
// BLSTM: emb gather -> fwd LSTM scan + bwd single-step -> [2048,512] @ fc_w^T
// B=16 S=128 V=32000 D=H=256.  Output logits [16,128,32000] fp32.
//
// R5 (k2h): k2g (455us, VGPR_Count=216) showed the 368-reg weight array was
// demoted (AGPR/scratch gymnastics: active-CU VALUBusy ~40% = ~3400cy/step
// VALU vs ~1200 designed) and h-broadcast burned 128 LDS insts/step.
// New scan: 512 thr/block (8 waves, 2/SIMD), thread owns 2 gate rows ->
// weights 184 VGPR (<=256 arch cap, no AGPR needed) + 9 chunks/row in LDS
// (147KB).  h broadcast via 1 cooperative ds_read_b64/wave + v_readlane ->
// SGPR operand of v_pk_fma_f16 (replaces 128 LDS insts with ~256cy VALU).
// __launch_bounds__(512,1): 1 block/CU -> 256-reg cap (R3's (512,2) capped
// at 128 and scratch-demoted everything).  2 lgkm-only barriers/step.
// ---------------------------------------------------------------------------

#define Bz 16
#define Sq 128
#define Vv 32000
#define Dd 256
#define Hh 256
#define Ktot  (2 * Hh)         // 512

#define NW_V 23   // weight chunks (uint4 = 8 f16) per row in VGPRs
#define NW_L 9    // weight chunks per row in LDS   (NW_V+NW_L == 32)

typedef __bf16 bf16x8 __attribute__((ext_vector_type(8)));
typedef float  f32x4  __attribute__((ext_vector_type(4)));
typedef _Float16 f16x2 __attribute__((ext_vector_type(2)));

__device__ __forceinline__ unsigned short f2bf(float x) {
  union { float f; unsigned u; } v; v.f = x;
  unsigned r = (v.u + 0x7FFFu + ((v.u >> 16) & 1u)) >> 16;
  return (unsigned short)r;
}
__device__ __forceinline__ float sigm(float x) { return 1.f / (1.f + __expf(-x)); }
__device__ __forceinline__ float tanh_(float x) { return 2.f / (1.f + __expf(-2.f * x)) - 1.f; }
__device__ __forceinline__ void fma4(float4& a, const float4 w, const float s) {
  a.x = fmaf(w.x, s, a.x); a.y = fmaf(w.y, s, a.y);
  a.z = fmaf(w.z, s, a.z); a.w = fmaf(w.w, s, a.w);
}
__device__ __forceinline__ unsigned pkh(float x, float y) {
  const unsigned short lo = __builtin_bit_cast(unsigned short, (_Float16)x);
  const unsigned short hi = __builtin_bit_cast(unsigned short, (_Float16)y);
  return ((unsigned)hi << 16) | (unsigned)lo;
}
// packed f16 MAC: acc(v2f16) += w(v2f16) * h(v2f16)  -> v_pk_fma_f16
__device__ __forceinline__ f16x2 fma2(unsigned w, unsigned h, f16x2 acc) {
  const f16x2 wv = __builtin_bit_cast(f16x2, w);
  const f16x2 hv = __builtin_bit_cast(f16x2, h);
#if __has_builtin(__builtin_elementwise_fma)
  return __builtin_elementwise_fma(wv, hv, acc);
#else
  return wv * hv + acc;   // -ffp-contract fuses to v_pk_fma_f16
#endif
}
// LDS-only barrier: order ds ops, do NOT drain vmcnt (keeps global prefetch
// in flight across the barrier).  Single asm block with "memory" clobber.
__device__ __forceinline__ void bar() {
  asm volatile("s_waitcnt lgkmcnt(0)\n\ts_barrier" ::: "memory");
}

// --------------------------------------------------------------------------
// K0: transpose+pack input weights to [k][j] float4 (i,f,g,o), fold biases.
// grid (256, 2), block 256.
// --------------------------------------------------------------------------
__global__ __launch_bounds__(256) void k0_pack(
    const float* __restrict__ w_ih_f, const float* __restrict__ w_ih_b,
    const float* __restrict__ b_ih_f, const float* __restrict__ b_hh_f,
    const float* __restrict__ b_ih_b, const float* __restrict__ b_hh_b,
    float4* __restrict__ wPackF, float4* __restrict__ wPackB,
    float4* __restrict__ biasF, float4* __restrict__ biasB)
{
  const int j = threadIdx.x;   // output column 0..255
  const int k = blockIdx.x;    // input dim 0..255
  const int g = blockIdx.y;    // 0: w_ih_f, 1: w_ih_b
  const float* src = (g == 0) ? w_ih_f : w_ih_b;
  float4* dst = (g == 0) ? wPackF : wPackB;
  float4 v;
  v.x = src[(j      ) * 256 + k];
  v.y = src[(j + 256) * 256 + k];
  v.z = src[(j + 512) * 256 + k];
  v.w = src[(j + 768) * 256 + k];
  dst[k * 256 + j] = v;
  if (k == 0 && g == 0) {
    float4 b;
    b.x = b_ih_f[j      ] + b_hh_f[j      ];
    b.y = b_ih_f[j + 256] + b_hh_f[j + 256];
    b.z = b_ih_f[j + 512] + b_hh_f[j + 512];
    b.w = b_ih_f[j + 768] + b_hh_f[j + 768];
    biasF[j] = b;
  }
  if (k == 0 && g == 1) {
    float4 b;
    b.x = b_ih_b[j      ] + b_hh_b[j      ];
    b.y = b_ih_b[j + 256] + b_hh_b[j + 256];
    b.z = b_ih_b[j + 512] + b_hh_b[j + 512];
    b.w = b_ih_b[j + 768] + b_hh_b[j + 768];
    biasB[j] = b;
  }
}

// --------------------------------------------------------------------------
// K1: embedding gather + input projections. grid (128, 2): y=0 -> xpG
// [m][1024] gate-row-major (biases folded), y=1 -> backward single-step
// cell -> hb (bf16, right half of the GEMM A matrix).
// --------------------------------------------------------------------------
__global__ __launch_bounds__(256) void k1_embproj(
    const int* __restrict__ x, const float* __restrict__ embed,
    const float4* __restrict__ wPackF, const float4* __restrict__ wPackB,
    const float4* __restrict__ biasF, const float4* __restrict__ biasB,
    float* __restrict__ xpG, unsigned short* __restrict__ outB)
{
  __shared__ __align__(16) float e[16][256];
  __shared__ int xi[16];
  const int j = threadIdx.x;
  const int m0 = blockIdx.x * 16;
  const int dir = blockIdx.y;
  if (j < 16) xi[j] = x[m0 + j];
  __syncthreads();
#pragma unroll
  for (int m = 0; m < 16; ++m) e[m][j] = embed[(size_t)xi[m] * Dd + j];
  __syncthreads();

  const float4* wP = dir ? wPackB : wPackF;
  float4 acc[16];
#pragma unroll
  for (int m = 0; m < 16; ++m) acc[m] = make_float4(0.f, 0.f, 0.f, 0.f);

  for (int k = 0; k < 256; k += 4) {
    const float4 w0 = wP[(k + 0) * 256 + j];
    const float4 w1 = wP[(k + 1) * 256 + j];
    const float4 w2 = wP[(k + 2) * 256 + j];
    const float4 w3 = wP[(k + 3) * 256 + j];
#pragma unroll
    for (int m = 0; m < 16; ++m) {
      const float4 e4 = *(const float4*)&e[m][k];
      fma4(acc[m], w0, e4.x); fma4(acc[m], w1, e4.y);
      fma4(acc[m], w2, e4.z); fma4(acc[m], w3, e4.w);
    }
  }

  if (dir == 0) {
    const float4 bv = biasF[j];
#pragma unroll
    for (int m = 0; m < 16; ++m) {
      float4 v = acc[m];
      float* xq = xpG + (size_t)(m0 + m) * 1024 + j;
      xq[0]   = v.x + bv.x;
      xq[256] = v.y + bv.y;
      xq[512] = v.z + bv.z;
      xq[768] = v.w + bv.w;
    }
  } else {
    const float4 bv = biasB[j];
#pragma unroll
    for (int m = 0; m < 16; ++m) {
      float4 v = acc[m];
      v.x += bv.x; v.y += bv.y; v.z += bv.z; v.w += bv.w;
      const float ig = sigm(v.x);
      const float gg = tanh_(v.z);
      const float og = sigm(v.w);
      const float hb = og * tanh_(ig * gg);
      outB[(size_t)(m0 + m) * Ktot + Hh + j] = f2bf(hb);
    }
  }
}

// --------------------------------------------------------------------------
// KW: W_hh fp32 [1024][256] -> packed f16, q-major layout [32][1024] uint4
// (q = k/8).  wq[q*1024 + row] = 8 f16 of row `row`, k in [8q, 8q+8).
// --------------------------------------------------------------------------
__global__ __launch_bounds__(256) void kw_cvt(const float4* __restrict__ s,
                                              uint4* __restrict__ d)
{
  const int g = blockIdx.x * 256 + threadIdx.x;   // 0..32767
  const int row = g & 1023;
  const int qq  = g >> 10;                        // 0..31
  const float4 a = s[row * 64 + qq * 2];
  const float4 b = s[row * 64 + qq * 2 + 1];
  uint4 r;
  r.x = pkh(a.x, a.y);
  r.y = pkh(a.z, a.w);
  r.z = pkh(b.x, b.y);
  r.w = pkh(b.z, b.w);
  d[g] = r;
}

// --------------------------------------------------------------------------
// K2h: forward LSTM scan, ONE block per batch (16 blocks x 512 threads,
// 8 waves = 2/SIMD).  Thread (u=tid&255, p=tid>>8) owns gate rows
// p*512+u (i or g) and p*512+256+u (f or o).
// Weights: 2x23 chunks in VGPRs (184 regs, fits the 256 arch cap with no
// AGPR/scratch), 2x9 chunks in LDS (147KB, lane-consecutive 16B).
// h broadcast: 1 cooperative ds_read_b64/wave (lane l holds h dwords
// 2l,2l+1), then v_readlane -> SGPR operand of v_pk_fma_f16.
// 2 lgkm-only barriers/step; xp prefetch (vmcnt) survives both.
// --------------------------------------------------------------------------
__global__ __launch_bounds__(512, 1) void k2h(
    const uint4* __restrict__ wq,     // [32][1024] uint4 packed f16 W_hh
    const float* __restrict__ xpG,    // [2048][1024]
    unsigned short* __restrict__ outB)
{
  __shared__ __align__(16) uint4 wl[2 * NW_L * 512];    // 147456 B
  __shared__ __align__(8)  float2 gox[256];             // g,o preacts (p=1 -> p=0)
  __shared__ __align__(8)  unsigned short hL[256];      // h_t as f16 bits

  const int tid = threadIdx.x;
  const int u = tid & 255;
  const int p = tid >> 8;
  const int b = blockIdx.x;
  const int rowA = p * 512 + u;         // gate i (p=0) / g (p=1)
  const int rowB = rowA + 256;          // gate f (p=0) / o (p=1)

  // one-time: weights into VGPRs (46 uint4 = 184 regs) -- coalesced
  uint4 wvA[NW_V], wvB[NW_V];
#pragma unroll
  for (int q = 0; q < NW_V; ++q) wvA[q] = wq[q * 1024 + rowA];
#pragma unroll
  for (int q = 0; q < NW_V; ++q) wvB[q] = wq[q * 1024 + rowB];
  // one-time: weight tail into LDS (18 uint4/thread)
#pragma unroll
  for (int j = 0; j < NW_L; ++j)
    wl[j * 512 + tid] = wq[(NW_V + j) * 1024 + rowA];
#pragma unroll
  for (int j = 0; j < NW_L; ++j)
    wl[(NW_L + j) * 512 + tid] = wq[(NW_V + j) * 1024 + rowB];

  const float* xpB = xpG + (size_t)b * Sq * 1024;
  float xa = xpB[rowA];                 // xp prefetch for t=0
  float xb = xpB[rowB];
  float cst = 0.f;                      // cell state (p=0 threads)
  unsigned short* oB = outB + (size_t)b * Sq * Ktot;

  unsigned hx = 0, hy = 0;              // lane-coop h: lane l holds dwords 2l,2l+1
  bar();                                // wl staged

  const f16x2 z2 = __builtin_bit_cast(f16x2, 0u);

#pragma unroll 1
  for (int t = 0; t < Sq; ++t) {
    // dot: 512 MACs/thread = 256 v_pk_fma_f16, h via readlane->SGPR.
    // Chunk q covers k in [8q,8q+8) = h dwords 4q..4q+3:
    //   dword 4q+d: lane 2q+(d>>1), reg (d&1 ? hy : hx).
    f16x2 aA0 = z2, aA1 = z2, aA2 = z2, aA3 = z2;
    f16x2 aB0 = z2, aB1 = z2, aB2 = z2, aB3 = z2;
#pragma unroll
    for (int q = 0; q < NW_V; ++q) {
      const unsigned s0 = __builtin_amdgcn_readlane(hx, 2 * q);
      const unsigned s1 = __builtin_amdgcn_readlane(hy, 2 * q);
      const unsigned s2 = __builtin_amdgcn_readlane(hx, 2 * q + 1);
      const unsigned s3 = __builtin_amdgcn_readlane(hy, 2 * q + 1);
      aA0 = fma2(wvA[q].x, s0, aA0); aB0 = fma2(wvB[q].x, s0, aB0);
      aA1 = fma2(wvA[q].y, s1, aA1); aB1 = fma2(wvB[q].y, s1, aB1);
      aA2 = fma2(wvA[q].z, s2, aA2); aB2 = fma2(wvB[q].z, s2, aB2);
      aA3 = fma2(wvA[q].w, s3, aA3); aB3 = fma2(wvB[q].w, s3, aB3);
    }
#pragma unroll
    for (int j = 0; j < NW_L; ++j) {
      const int q = NW_V + j;
      const uint4 wA = wl[j * 512 + tid];              // conflict-free 16B/lane
      const uint4 wB = wl[(NW_L + j) * 512 + tid];
      const unsigned s0 = __builtin_amdgcn_readlane(hx, 2 * q);
      const unsigned s1 = __builtin_amdgcn_readlane(hy, 2 * q);
      const unsigned s2 = __builtin_amdgcn_readlane(hx, 2 * q + 1);
      const unsigned s3 = __builtin_amdgcn_readlane(hy, 2 * q + 1);
      aA0 = fma2(wA.x, s0, aA0); aB0 = fma2(wB.x, s0, aB0);
      aA1 = fma2(wA.y, s1, aA1); aB1 = fma2(wB.y, s1, aB1);
      aA2 = fma2(wA.z, s2, aA2); aB2 = fma2(wB.z, s2, aB2);
      aA3 = fma2(wA.w, s3, aA3); aB3 = fma2(wB.w, s3, aB3);
    }
    const float preA = xa
        + (((float)aA0.x + (float)aA0.y) + ((float)aA1.x + (float)aA1.y))
        + (((float)aA2.x + (float)aA2.y) + ((float)aA3.x + (float)aA3.y));
    const float preB = xb
        + (((float)aB0.x + (float)aB0.y) + ((float)aB1.x + (float)aB1.y))
        + (((float)aB2.x + (float)aB2.y) + ((float)aB3.x + (float)aB3.y));

    // prefetch next step's xp (vmcnt -- survives the lgkm-only barriers)
    {
      const float* xn = xpB + (size_t)((t + 1) & (Sq - 1)) * 1024;
      xa = xn[rowA]; xb = xn[rowB];
    }

    if (p) gox[u] = make_float2(preA, preB);   // publish g,o preacts
    bar();   // #1

    if (!p) {
      const float2 go = gox[u];
      const float ig = sigm(preA);        // i
      const float fg = sigm(preB);        // f
      const float gg = tanh_(go.x);       // g
      const float og = sigm(go.y);        // o
      cst = fg * cst + ig * gg;
      const float hn = og * tanh_(cst);
      hL[u] = __builtin_bit_cast(unsigned short, (_Float16)hn);
      oB[t * Ktot + u] = f2bf(hn);
    }
    bar();   // #2: h_t published

    // cooperative h pickup for step t+1: 8B/lane, 2-way bank alias (free)
    {
      const uint2 hv2 = *(const uint2*)((const char*)hL + ((tid & 63) * 8));
      hx = hv2.x; hy = hv2.y;
    }
  }
}

// --------------------------------------------------------------------------
// K3: fc_w fp32 -> bf16.  16,384,000 elems; 4 per thread.
// --------------------------------------------------------------------------
__global__ __launch_bounds__(256) void k3_cvt(const float4* __restrict__ s,
                                              uint2* __restrict__ d)
{
  const int i = blockIdx.x * 256 + threadIdx.x;
  const float4 v = s[i];
  uint2 r;
  r.x = (unsigned)f2bf(v.x) | ((unsigned)f2bf(v.y) << 16);
  r.y = (unsigned)f2bf(v.z) | ((unsigned)f2bf(v.w) << 16);
  d[i] = r;
}

// --------------------------------------------------------------------------
// K4: logits = [2048,512](bf16) x fc_w^T (fc_w [32000,512] bf16, B^T layout)
// + fc_b.  128x128 tile, BK=64, 4 waves, global_load_lds width-16 staging.
// --------------------------------------------------------------------------
__device__ __forceinline__ void load_lds_16(const void* g, void* l) {
  __builtin_amdgcn_global_load_lds(
      (const __attribute__((address_space(1))) unsigned int*)g,
      (__attribute__((address_space(3))) unsigned int*)l, 16, 0, 0);
}

__global__ __launch_bounds__(256) void k4_gemm(
    const unsigned short* __restrict__ A,   // [2048][512] bf16
    const unsigned short* __restrict__ Bm,  // [32000][512] bf16
    const float* __restrict__ fcb,          // [32000]
    float* __restrict__ out)                // [2048][32000]
{
  __shared__ __align__(16) char smem[32768];
  const int tid  = threadIdx.x;
  const int wave = tid >> 6;
  const int lane = tid & 63;
  const int bm = blockIdx.x;      // 0..15  (M tiles)
  const int bn = blockIdx.y;      // 0..249 (N tiles)
  const int wm = (wave >> 1) * 64;
  const int wn = (wave & 1) * 64;
  const int quad = lane >> 4;
  const int r16  = lane & 15;

  f32x4 acc[4][4] = {};

  const unsigned short* Ag = A  + ((size_t)(bm * 128) + (tid >> 3)) * Ktot + (tid & 7) * 8;
  const unsigned short* Bg = Bm + ((size_t)(bn * 128) + (tid >> 3)) * Ktot + (tid & 7) * 8;
  char* AsW = smem + wave * 1024;
  char* BsW = smem + 16384 + wave * 1024;

  for (int kt = 0; kt < 8; ++kt) {
    const int k0 = kt * 64;
#pragma unroll
    for (int r = 0; r < 4; ++r) {
      load_lds_16(Ag + (size_t)r * 32 * Ktot + k0, AsW + r * 4096);
      load_lds_16(Bg + (size_t)r * 32 * Ktot + k0, BsW + r * 4096);
    }
    __syncthreads();
#pragma unroll
    for (int kk = 0; kk < 2; ++kk) {
      bf16x8 af[4], bfr[4];
#pragma unroll
      for (int i = 0; i < 4; ++i) {
        const int rowA = wm + i * 16 + r16;
        af[i] = *(const bf16x8*)(smem + rowA * 128 + kk * 64 + quad * 16);
        const int rowB = wn + i * 16 + r16;
        bfr[i] = *(const bf16x8*)(smem + 16384 + rowB * 128 + kk * 64 + quad * 16);
      }
#pragma unroll
      for (int i = 0; i < 4; ++i)
#pragma unroll
        for (int j = 0; j < 4; ++j)
          acc[i][j] = __builtin_amdgcn_mfma_f32_16x16x32_bf16(af[i], bfr[j], acc[i][j], 0, 0, 0);
    }
    __syncthreads();
  }

#pragma unroll
  for (int j = 0; j < 4; ++j) {
    const int col = bn * 128 + wn + j * 16 + r16;
    const float bias = fcb[col];
#pragma unroll
    for (int i = 0; i < 4; ++i) {
      const int row0 = bm * 128 + wm + i * 16 + quad * 4;
#pragma unroll
      for (int r = 0; r < 4; ++r) {
        out[(size_t)(row0 + r) * Vv + col] = acc[i][j][r] + bias;
      }
    }
  }
}

// --------------------------------------------------------------------------
extern "C" void kernel_launch(void* const* d_in, const int* in_sizes, int n_in,
                              void* d_out, int out_size, void* d_ws, size_t ws_size,
                              hipStream_t stream) {
  const int*   x      = (const int*)d_in[0];
  const float* embed  = (const float*)d_in[1];
  const float* w_ih_f = (const float*)d_in[2];
  const float* w_hh_f = (const float*)d_in[3];
  const float* b_ih_f = (const float*)d_in[4];
  const float* b_hh_f = (const float*)d_in[5];
  const float* w_ih_b = (const float*)d_in[6];
  // d_in[7] = w_hh_b: unused (backward direction is a zero-state single step)
  const float* b_ih_b = (const float*)d_in[8];
  const float* b_hh_b = (const float*)d_in[9];
  const float* fc_w   = (const float*)d_in[10];
  const float* fc_b   = (const float*)d_in[11];
  float* out = (float*)d_out;

  // Workspace layout (peak 45.4 MB; wq overlays wPackF which is dead after
  // k1 -- kw_cvt MUST launch after k1):
  char* ws = (char*)d_ws;
  float4* wPackF = (float4*)(ws + 0x000000);            // 1 MB   (k0 w, k1 r)
  float4* wPackB = (float4*)(ws + 0x100000);            // 1 MB   (k0 w, k1 r)
  uint4*  wq     = (uint4*)(ws + 0x000000);             // 512 KB (kw w, k2 r)
  float*  xpG    = (float*)(ws + 0x200000);             // 8 MB   (k1 w, k2 r)
  float4* biasF  = (float4*)(ws + 0xA00000);            // 4 KB
  float4* biasB  = (float4*)(ws + 0xA01000);            // 4 KB
  unsigned short* outB = (unsigned short*)(ws + 0xA05000);   // 2 MB [2048][512]
  unsigned short* fcwB = (unsigned short*)(ws + 0xC05000);   // 31.25 MiB

  k0_pack<<<dim3(256, 2), 256, 0, stream>>>(w_ih_f, w_ih_b,
                                            b_ih_f, b_hh_f, b_ih_b, b_hh_b,
                                            wPackF, wPackB, biasF, biasB);
  k3_cvt<<<16000, 256, 0, stream>>>((const float4*)fc_w, (uint2*)fcwB);
  k1_embproj<<<dim3(128, 2), 256, 0, stream>>>(x, embed, wPackF, wPackB,
                                               biasF, biasB, xpG, outB);
  kw_cvt<<<128, 256, 0, stream>>>((const float4*)w_hh_f, wq);
  k2h<<<16, 512, 0, stream>>>(wq, xpG, outB);
  k4_gemm<<<dim3(16, 250), 256, 0, stream>>>(outB, fcwB, fc_b, out);
}